// Round 9
// baseline (164.516 us; speedup 1.0000x reference)
//
#include <hip/hip_runtime.h>

// Problem constants (fixed by the reference): B=16 lists, N=1024, D=256.
#define BL 16
#define NL 1024
#define DD 256

typedef short bf16x8 __attribute__((ext_vector_type(8)));
typedef float f32x4 __attribute__((ext_vector_type(4)));

static __device__ __forceinline__ short f32_to_bf16(float f) {
  union { float f; unsigned u; } v; v.f = f;
  unsigned r = (v.u + 0x7FFFu + ((v.u >> 16) & 1u)) >> 16;  // RNE
  return (short)r;
}

// Async 16B global -> LDS. LDS dest must be wave-uniform base + lane*16
// (m104/m108). Global source address IS per-lane -> pre-swizzled source.
static __device__ __forceinline__ void g2l16(const short* g, short* l) {
  __builtin_amdgcn_global_load_lds(
      (const __attribute__((address_space(1))) void*)g,
      (__attribute__((address_space(3))) void*)l, 16, 0, 0);
}

// ---- Kernel 1: prep. Blocks [0,4096): X fp32->bf16. [4096,4608): W transpose.
__global__ __launch_bounds__(256) void k_prep(const float* __restrict__ X,
                                              const float* __restrict__ Wu,
                                              const float* __restrict__ Wl,
                                              short* __restrict__ Xb,
                                              short* __restrict__ WTu,
                                              short* __restrict__ WTl) {
  const int bid = blockIdx.x;
  if (bid < 4096) {
    int i = bid * 256 + threadIdx.x;  // float4 groups over 16384*256 floats
    const float4 v = ((const float4*)X)[i];
    short4 o;
    o.x = f32_to_bf16(v.x); o.y = f32_to_bf16(v.y);
    o.z = f32_to_bf16(v.z); o.w = f32_to_bf16(v.w);
    ((short4*)Xb)[i] = o;
  } else {
    const int id = bid - 4096;           // [0,512)
    const int z = id >> 8, d = id & 255; // matrix, source row of W
    const float* W = z ? Wl : Wu;
    short* WT = z ? WTl : WTu;
    const int e = threadIdx.x;
    WT[e * DD + d] = f32_to_bf16(W[d * DD + e]);  // WT[e][d] = W[d][e]
  }
}

// ---- Kernel 2: fused stage1+stage2.
// Block = (list b, 128-row strip pt in [0,8), q-half qh). 256 blocks x 1024 thr
// = 1 block/CU, 4 waves/SIMD. LDS 128 KB: BufL (X-stage -> Y_L -> epilogue
// scratch) + BufU (Y_upper).
// Traffic model (R3-R8: dur = bytes / ~5.5 TB/s fabric): B-rereads halved to
// 64 MB (256 KB/block); stores emitted as full 128B lines via LDS-transpose
// epilogue (R6 counted 110 MB for 64 MB of output: 64B sector halves from
// different instructions do not merge); all stores after all reads.
// bid = z*16 + b -> XCD = bid%8 = b%8: lists pinned per XCD as before.
__global__ __launch_bounds__(1024, 4) void k_fused(const short* __restrict__ Xb,
                                                   const short* __restrict__ WTu,
                                                   const short* __restrict__ WTl,
                                                   const float* __restrict__ bu_p,
                                                   const float* __restrict__ bl_p,
                                                   float* __restrict__ out) {
  __shared__ short BufL[128 * 256];  // 64 KB: Xp stage -> Y_L -> f32 scratch
  __shared__ short BufU[128 * 256];  // 64 KB: Y_upper

  const int bid = blockIdx.x;
  const int b = bid & 15, z = bid >> 4;   // z in [0,16)
  const int pt = z >> 1, qh = z & 1;      // 128-row strip, q-half
  const int t = threadIdx.x, lane = t & 63, w = t >> 6;  // w in [0,16)
  const int r = lane & 15, quad = lane >> 4;
  const size_t listoff = (size_t)b * NL * DD;
  const short* Ap = Xb + listoff + (size_t)pt * 128 * DD;  // 128 x 256 bf16

  // ---- stage Xp into BufL, XOR-swizzled via pre-swizzled global source ----
  // 4096 16B-chunks (32/row); read at (row*512+kb)^((row&7)<<4) -> src c^((c>>5)&7)
#pragma unroll
  for (int i = 0; i < 4; ++i) {
    const int c = i * 1024 + t;  // per wave: uniform base + lane*16
    const int src = c ^ ((c >> 5) & 7);
    g2l16(Ap + src * 8, BufL + c * 8);
  }
  __syncthreads();

  // ---- phase 1: Y = Xp * W (both matrices); wave w -> cols [w*16,+16) ----
  const int n0 = w * 16;
  f32x4 aU[8] = {}, aL[8] = {};
#pragma unroll
  for (int ks = 0; ks < 8; ++ks) {
    bf16x8 af[8];
#pragma unroll
    for (int mt = 0; mt < 8; ++mt) {
      const int row = mt * 16 + r;
      const int abyte = (row * 512 + ks * 64 + quad * 16) ^ ((row & 7) << 4);
      af[mt] = *(const bf16x8*)((const char*)BufL + abyte);
    }
    const int off = (n0 + r) * DD + ks * 32 + quad * 8;
    const bf16x8 bfu = *(const bf16x8*)(WTu + off);
    const bf16x8 bfl = *(const bf16x8*)(WTl + off);
#pragma unroll
    for (int mt = 0; mt < 8; ++mt) {
      aU[mt] = __builtin_amdgcn_mfma_f32_16x16x32_bf16(af[mt], bfu, aU[mt], 0, 0, 0);
      aL[mt] = __builtin_amdgcn_mfma_f32_16x16x32_bf16(af[mt], bfl, aL[mt], 0, 0, 0);
    }
  }
  // Y_upper -> BufU (BufU not read yet: safe before barrier).
  // D[m][n]: row = mt*16 + quad*4 + i, col = n0 + r.
#pragma unroll
  for (int mt = 0; mt < 8; ++mt)
#pragma unroll
    for (int i = 0; i < 4; ++i) {
      const int row = mt * 16 + quad * 4 + i;
      const int byte = (row * 512 + (n0 + r) * 2) ^ ((row & 7) << 4);
      *(short*)((char*)BufU + byte) = f32_to_bf16(aU[mt][i]);
    }
  __syncthreads();  // all Xp reads done -> BufL reusable
  // Y_lower -> BufL (was held in regs across the barrier).
#pragma unroll
  for (int mt = 0; mt < 8; ++mt)
#pragma unroll
    for (int i = 0; i < 4; ++i) {
      const int row = mt * 16 + quad * 4 + i;
      const int byte = (row * 512 + (n0 + r) * 2) ^ ((row & 7) << 4);
      *(short*)((char*)BufL + byte) = f32_to_bf16(aL[mt][i]);
    }
  __syncthreads();  // Yu + Yl published

  // ---- phase 2: wave w = (p-half h, q-tile j); 64x64 output tile ----
  const float ub = bu_p[0], lb = bl_p[0];
  const int h = w >> 3, j = w & 7;
  const int p0 = pt * 128 + h * 64;
  const int qt = qh * 8 + j, q0 = qt * 64;
  const short* Bg = Xb + listoff + (size_t)qt * 64 * DD;
  const bool upper = (q0 >= p0);
  const short* YA = upper ? BufU : BufL;
  const int rbase = h * 64;

  f32x4 acc[4][4] = {};  // [nt][mt]: D row <- q (B rows), col <- p (Y rows)
#pragma unroll
  for (int ks = 0; ks < 8; ++ks) {
    bf16x8 af[4], bf[4];
#pragma unroll
    for (int mt = 0; mt < 4; ++mt) {
      const int row = rbase + mt * 16 + r;
      const int abyte = (row * 512 + ks * 64 + quad * 16) ^ ((row & 7) << 4);
      af[mt] = *(const bf16x8*)((const char*)YA + abyte);
    }
#pragma unroll
    for (int nt = 0; nt < 4; ++nt)
      bf[nt] = *(const bf16x8*)(Bg + (size_t)(nt * 16 + r) * DD + ks * 32 + quad * 8);
#pragma unroll
    for (int nt = 0; nt < 4; ++nt)
#pragma unroll
      for (int mt = 0; mt < 4; ++mt)
        acc[nt][mt] = __builtin_amdgcn_mfma_f32_16x16x32_bf16(bf[nt], af[mt],
                                                              acc[nt][mt], 0, 0, 0);
  }

  float bias = upper ? ub : lb;
  if (q0 == p0) {  // diagonal tile: recompute with Y_L, merge in registers
    f32x4 accL[4][4] = {};
#pragma unroll
    for (int ks = 0; ks < 8; ++ks) {
      bf16x8 af[4], bf[4];
#pragma unroll
      for (int mt = 0; mt < 4; ++mt) {
        const int row = rbase + mt * 16 + r;
        const int abyte = (row * 512 + ks * 64 + quad * 16) ^ ((row & 7) << 4);
        af[mt] = *(const bf16x8*)((const char*)BufL + abyte);
      }
#pragma unroll
      for (int nt = 0; nt < 4; ++nt)
        bf[nt] = *(const bf16x8*)(Bg + (size_t)(nt * 16 + r) * DD + ks * 32 + quad * 8);
#pragma unroll
      for (int nt = 0; nt < 4; ++nt)
#pragma unroll
        for (int mt = 0; mt < 4; ++mt)
          accL[nt][mt] = __builtin_amdgcn_mfma_f32_16x16x32_bf16(bf[nt], af[mt],
                                                                 accL[nt][mt], 0, 0, 0);
    }
#pragma unroll
    for (int nt = 0; nt < 4; ++nt)
#pragma unroll
      for (int mt = 0; mt < 4; ++mt)
#pragma unroll
        for (int i = 0; i < 4; ++i) {
          const int q = q0 + nt * 16 + quad * 4 + i;
          const int p = p0 + mt * 16 + r;
          acc[nt][mt][i] = (q >= p) ? acc[nt][mt][i] + ub : accL[nt][mt][i] + lb;
        }
    bias = 0.f;
  }

  // ---- epilogue: all Y reads done -> BufL becomes per-wave f32 scratch.
  // Transpose each 16x64 chunk through LDS so every global store instruction
  // covers 4 rows x 256B (two full 128B lines per row).
  __syncthreads();
  float* scr = (float*)BufL + w * 1024;  // 4 KB per wave
  float* Ob = out + (size_t)b * NL * NL;
#pragma unroll
  for (int mt = 0; mt < 4; ++mt) {
    // scatter into scratch: row r (stride 256B), float col nt*16+quad*4+i
#pragma unroll
    for (int nt = 0; nt < 4; ++nt) {
      f32x4 v;
#pragma unroll
      for (int i = 0; i < 4; ++i) v[i] = acc[nt][mt][i] + bias;
      const int sb = (r * 256 + nt * 64 + quad * 16) ^ ((r & 7) << 4);
      *(f32x4*)((char*)scr + sb) = v;
    }
    // gather rows: inst k covers scratch rows k*4+quad, slots r -> 4 rows x 256B
#pragma unroll
    for (int k = 0; k < 4; ++k) {
      const int row = k * 4 + quad;
      const int rb = (row * 256 + r * 16) ^ ((row & 7) << 4);
      const f32x4 v = *(const f32x4*)((const char*)scr + rb);
      *(f32x4*)(Ob + (size_t)(p0 + mt * 16 + row) * NL + q0 + r * 4) = v;
    }
  }
}

extern "C" void kernel_launch(void* const* d_in, const int* in_sizes, int n_in,
                              void* d_out, int out_size, void* d_ws, size_t ws_size,
                              hipStream_t stream) {
  const float* feats = (const float*)d_in[0];   // [B*N, D] fp32
  const float* Wu    = (const float*)d_in[1];   // [1, D, D]
  const float* bu    = (const float*)d_in[2];   // [1]
  const float* Wl    = (const float*)d_in[3];   // [1, D, D]
  const float* bl    = (const float*)d_in[4];   // [1]
  float* out = (float*)d_out;                   // [B, N, N] fp32

  char* ws = (char*)d_ws;
  short* Xb  = (short*)(ws);                                   // 8 MB bf16 X
  short* WTu = (short*)(ws + (size_t)8 * 1024 * 1024);         // 128 KB
  short* WTl = (short*)(ws + (size_t)8 * 1024 * 1024 + DD * DD * 2);

  // Prep: X->bf16 (4096 blocks) + W transpose (512 blocks), one dispatch.
  k_prep<<<4096 + 512, 256, 0, stream>>>(feats, Wu, Wl, Xb, WTu, WTl);

  // Fused stage1+stage2: 256 blocks (8 strips x 2 q-halves x 16 lists),
  // 1024 threads, 128 KB LDS -> 1 block/CU. XCD = bid%8 = b%8.
  k_fused<<<256, 1024, 0, stream>>>(Xb, WTu, WTl, bu, bl, out);
}

// Round 10
// 162.982 us; speedup vs baseline: 1.0094x; 1.0094x over previous
//
#include <hip/hip_runtime.h>

// Problem constants (fixed by the reference): B=16 lists, N=1024, D=256.
#define BL 16
#define NL 1024
#define DD 256

typedef short bf16x8 __attribute__((ext_vector_type(8)));
typedef float f32x4 __attribute__((ext_vector_type(4)));

static __device__ __forceinline__ short f32_to_bf16(float f) {
  union { float f; unsigned u; } v; v.f = f;
  unsigned r = (v.u + 0x7FFFu + ((v.u >> 16) & 1u)) >> 16;  // RNE
  return (short)r;
}

// Async 16B global -> LDS. LDS dest must be wave-uniform base + lane*16
// (m104/m108). Global source address IS per-lane -> pre-swizzled source.
static __device__ __forceinline__ void g2l16(const short* g, short* l) {
  __builtin_amdgcn_global_load_lds(
      (const __attribute__((address_space(1))) void*)g,
      (__attribute__((address_space(3))) void*)l, 16, 0, 0);
}

// ---- Kernel 1: prep. Blocks [0,4096): X fp32->bf16. [4096,4608): W transpose.
__global__ __launch_bounds__(256) void k_prep(const float* __restrict__ X,
                                              const float* __restrict__ Wu,
                                              const float* __restrict__ Wl,
                                              short* __restrict__ Xb,
                                              short* __restrict__ WTu,
                                              short* __restrict__ WTl) {
  const int bid = blockIdx.x;
  if (bid < 4096) {
    int i = bid * 256 + threadIdx.x;  // float4 groups over 16384*256 floats
    const float4 v = ((const float4*)X)[i];
    short4 o;
    o.x = f32_to_bf16(v.x); o.y = f32_to_bf16(v.y);
    o.z = f32_to_bf16(v.z); o.w = f32_to_bf16(v.w);
    ((short4*)Xb)[i] = o;
  } else {
    const int id = bid - 4096;           // [0,512)
    const int z = id >> 8, d = id & 255; // matrix, source row of W
    const float* W = z ? Wl : Wu;
    short* WT = z ? WTl : WTu;
    const int e = threadIdx.x;
    WT[e * DD + d] = f32_to_bf16(W[d * DD + e]);  // WT[e][d] = W[d][e]
  }
}

// ---- Kernel 2: fused stage1+stage2.
// Block = (list b, 128-row strip pt in [0,8), q-half qh). 256 blocks x 1024 thr
// = 1 block/CU. LDS 128 KB: BufL (X-stage -> Y_L) + BufU (Y_upper).
// R9 A/B result: 128-row strips halve fabric-side B-rereads (kept), but the
// end-burst LDS-transpose epilogue caused 3.5x write amplification (WRITE
// 224 MB) + L2/L3 thrash (FETCH 36 MB) -> R10 restores R6's inline per-wave
// stores (WRITE was 110 MB there), no barrier before stores, no scratch.
// bid = z*16 + b -> XCD = bid%8 = b%8: lists pinned per XCD as before.
__global__ __launch_bounds__(1024, 4) void k_fused(const short* __restrict__ Xb,
                                                   const short* __restrict__ WTu,
                                                   const short* __restrict__ WTl,
                                                   const float* __restrict__ bu_p,
                                                   const float* __restrict__ bl_p,
                                                   float* __restrict__ out) {
  __shared__ short BufL[128 * 256];  // 64 KB: Xp stage -> Y_L
  __shared__ short BufU[128 * 256];  // 64 KB: Y_upper

  const int bid = blockIdx.x;
  const int b = bid & 15, z = bid >> 4;   // z in [0,16)
  const int pt = z >> 1, qh = z & 1;      // 128-row strip, q-half
  const int t = threadIdx.x, lane = t & 63, w = t >> 6;  // w in [0,16)
  const int r = lane & 15, quad = lane >> 4;
  const size_t listoff = (size_t)b * NL * DD;
  const short* Ap = Xb + listoff + (size_t)pt * 128 * DD;  // 128 x 256 bf16

  // ---- stage Xp into BufL, XOR-swizzled via pre-swizzled global source ----
  // 4096 16B-chunks (32/row); read at (row*512+kb)^((row&7)<<4) -> src c^((c>>5)&7)
#pragma unroll
  for (int i = 0; i < 4; ++i) {
    const int c = i * 1024 + t;  // per wave: uniform base + lane*16
    const int src = c ^ ((c >> 5) & 7);
    g2l16(Ap + src * 8, BufL + c * 8);
  }
  __syncthreads();

  // ---- phase 1: Y = Xp * W (both matrices); wave w -> cols [w*16,+16) ----
  const int n0 = w * 16;
  {
    f32x4 aU[8] = {}, aL[8] = {};
#pragma unroll
    for (int ks = 0; ks < 8; ++ks) {
      bf16x8 af[8];
#pragma unroll
      for (int mt = 0; mt < 8; ++mt) {
        const int row = mt * 16 + r;
        const int abyte = (row * 512 + ks * 64 + quad * 16) ^ ((row & 7) << 4);
        af[mt] = *(const bf16x8*)((const char*)BufL + abyte);
      }
      const int off = (n0 + r) * DD + ks * 32 + quad * 8;
      const bf16x8 bfu = *(const bf16x8*)(WTu + off);
      const bf16x8 bfl = *(const bf16x8*)(WTl + off);
#pragma unroll
      for (int mt = 0; mt < 8; ++mt) {
        aU[mt] = __builtin_amdgcn_mfma_f32_16x16x32_bf16(af[mt], bfu, aU[mt], 0, 0, 0);
        aL[mt] = __builtin_amdgcn_mfma_f32_16x16x32_bf16(af[mt], bfl, aL[mt], 0, 0, 0);
      }
    }
    // Y_upper -> BufU (BufU not read yet: safe before barrier).
#pragma unroll
    for (int mt = 0; mt < 8; ++mt)
#pragma unroll
      for (int i = 0; i < 4; ++i) {
        const int row = mt * 16 + quad * 4 + i;
        const int byte = (row * 512 + (n0 + r) * 2) ^ ((row & 7) << 4);
        *(short*)((char*)BufU + byte) = f32_to_bf16(aU[mt][i]);
      }
    __syncthreads();  // all Xp reads done -> BufL reusable
    // Y_lower -> BufL (held in regs across the barrier).
#pragma unroll
    for (int mt = 0; mt < 8; ++mt)
#pragma unroll
      for (int i = 0; i < 4; ++i) {
        const int row = mt * 16 + quad * 4 + i;
        const int byte = (row * 512 + (n0 + r) * 2) ^ ((row & 7) << 4);
        *(short*)((char*)BufL + byte) = f32_to_bf16(aL[mt][i]);
      }
  }
  __syncthreads();  // Yu + Yl published; last barrier in the kernel

  // ---- phase 2: wave w = (p-half h, q-tile j); one 64x64 output tile ----
  const float ub = bu_p[0], lb = bl_p[0];
  const int h = w >> 3, j = w & 7;
  const int p0 = pt * 128 + h * 64;       // global p base
  const int rbase = h * 64;               // row base within Y buffers
  const int ptile = pt * 2 + h;           // p in units of 64-tiles
  const int qt = qh * 8 + j, q0 = qt * 64;
  const short* Bg = Xb + listoff + (size_t)qt * 64 * DD;
  const bool upper = (qt >= ptile);
  const short* YA = upper ? BufU : BufL;

  f32x4 acc[4][4] = {};  // [nt][mt]: D row <- q (B rows), col <- p (Y rows)
#pragma unroll
  for (int ks = 0; ks < 8; ++ks) {
    bf16x8 af[4], bf[4];
#pragma unroll
    for (int mt = 0; mt < 4; ++mt) {
      const int row = rbase + mt * 16 + r;
      const int abyte = (row * 512 + ks * 64 + quad * 16) ^ ((row & 7) << 4);
      af[mt] = *(const bf16x8*)((const char*)YA + abyte);
    }
#pragma unroll
    for (int nt = 0; nt < 4; ++nt)
      bf[nt] = *(const bf16x8*)(Bg + (size_t)(nt * 16 + r) * DD + ks * 32 + quad * 8);
#pragma unroll
    for (int nt = 0; nt < 4; ++nt)
#pragma unroll
      for (int mt = 0; mt < 4; ++mt)
        acc[nt][mt] = __builtin_amdgcn_mfma_f32_16x16x32_bf16(bf[nt], af[mt],
                                                              acc[nt][mt], 0, 0, 0);
  }

  float bias = upper ? ub : lb;
  if (qt == ptile) {  // diagonal tile: recompute with Y_L, merge in registers
    f32x4 accL[4][4] = {};
#pragma unroll
    for (int ks = 0; ks < 8; ++ks) {
      bf16x8 af[4], bf[4];
#pragma unroll
      for (int mt = 0; mt < 4; ++mt) {
        const int row = rbase + mt * 16 + r;
        const int abyte = (row * 512 + ks * 64 + quad * 16) ^ ((row & 7) << 4);
        af[mt] = *(const bf16x8*)((const char*)BufL + abyte);
      }
#pragma unroll
      for (int nt = 0; nt < 4; ++nt)
        bf[nt] = *(const bf16x8*)(Bg + (size_t)(nt * 16 + r) * DD + ks * 32 + quad * 8);
#pragma unroll
      for (int nt = 0; nt < 4; ++nt)
#pragma unroll
        for (int mt = 0; mt < 4; ++mt)
          accL[nt][mt] = __builtin_amdgcn_mfma_f32_16x16x32_bf16(bf[nt], af[mt],
                                                                 accL[nt][mt], 0, 0, 0);
    }
#pragma unroll
    for (int nt = 0; nt < 4; ++nt)
#pragma unroll
      for (int mt = 0; mt < 4; ++mt)
#pragma unroll
        for (int i = 0; i < 4; ++i) {
          const int q = q0 + nt * 16 + quad * 4 + i;
          const int p = p0 + mt * 16 + r;
          acc[nt][mt][i] = (q >= p) ? acc[nt][mt][i] + ub : accL[nt][mt][i] + lb;
        }
    bias = 0.f;
  }

  // ---- inline per-wave stores (no barrier): lane -> row p0+mt*16+r,
  // 4 consecutive q per f32x4; wave skew spreads the write stream.
  float* Ob = out + (size_t)b * NL * NL;
#pragma unroll
  for (int mt = 0; mt < 4; ++mt) {
    float* row = Ob + (size_t)(p0 + mt * 16 + r) * NL;
#pragma unroll
    for (int nt = 0; nt < 4; ++nt) {
      f32x4 v;
#pragma unroll
      for (int i = 0; i < 4; ++i) v[i] = acc[nt][mt][i] + bias;
      *(f32x4*)(row + q0 + nt * 16 + quad * 4) = v;
    }
  }
}

extern "C" void kernel_launch(void* const* d_in, const int* in_sizes, int n_in,
                              void* d_out, int out_size, void* d_ws, size_t ws_size,
                              hipStream_t stream) {
  const float* feats = (const float*)d_in[0];   // [B*N, D] fp32
  const float* Wu    = (const float*)d_in[1];   // [1, D, D]
  const float* bu    = (const float*)d_in[2];   // [1]
  const float* Wl    = (const float*)d_in[3];   // [1, D, D]
  const float* bl    = (const float*)d_in[4];   // [1]
  float* out = (float*)d_out;                   // [B, N, N] fp32

  char* ws = (char*)d_ws;
  short* Xb  = (short*)(ws);                                   // 8 MB bf16 X
  short* WTu = (short*)(ws + (size_t)8 * 1024 * 1024);         // 128 KB
  short* WTl = (short*)(ws + (size_t)8 * 1024 * 1024 + DD * DD * 2);

  // Prep: X->bf16 (4096 blocks) + W transpose (512 blocks), one dispatch.
  k_prep<<<4096 + 512, 256, 0, stream>>>(feats, Wu, Wl, Xb, WTu, WTl);

  // Fused stage1+stage2: 256 blocks (8 strips x 2 q-halves x 16 lists),
  // 1024 threads, 128 KB LDS -> 1 block/CU. XCD = bid%8 = b%8.
  k_fused<<<256, 1024, 0, stream>>>(Xb, WTu, WTl, bu, bl, out);
}